// Round 1
// baseline (1370.712 us; speedup 1.0000x reference)
//
#include <hip/hip_runtime.h>
#include <cmath>

#define TOK   49
#define WDIM  192
#define NHEADS 6
#define HID   768

typedef __bf16 bf16_t;
typedef bf16_t bf16x8 __attribute__((ext_vector_type(8)));
typedef float  f32x4  __attribute__((ext_vector_type(4)));

#define XLD 200   // xln leading dim (bf16 elems): 192+8 pad -> 2-way (free) LDS banks
#define QLD 40    // q/k leading dim: 32+8
#define VLD 72    // vT leading dim: 64+8
#define PLD 40    // per-wave P buffer leading dim
#define HLD 264   // mlp hbuf leading dim: 256+8

__device__ __forceinline__ f32x4 mfma16(bf16x8 a, bf16x8 b, f32x4 c) {
    return __builtin_amdgcn_mfma_f32_16x16x32_bf16(a, b, c, 0, 0, 0);
}

// ---------------- prep: pack fp32 weight W[K][N] into bf16 MFMA-B fragment order ----
// packed index p = ((nt*KB + kb)*64 + lane)*8 + j  maps to  W[k = kb*32 + (lane>>4)*8 + j][n = nt*16 + (lane&15)]
__global__ void pack_w(const float* __restrict__ W, bf16_t* __restrict__ out,
                       int K, int N, int total) {
    int p = blockIdx.x * 256 + threadIdx.x;
    if (p >= total) return;
    int j    = p & 7;
    int lane = (p >> 3) & 63;
    int kbnt = p >> 9;
    int KB   = K >> 5;
    int kb   = kbnt % KB;
    int nt   = kbnt / KB;
    int n = nt * 16 + (lane & 15);
    int k = kb * 32 + (lane >> 4) * 8 + j;
    out[p] = (bf16_t)W[k * N + n];
}

// ---------------- prep: bias6[h][m][n] = bias_table[rel_index[m][n]][h] -------------
__global__ void make_bias6(const float* __restrict__ table, const int* __restrict__ rel,
                           float* __restrict__ out) {
    int p = blockIdx.x * 256 + threadIdx.x;
    if (p >= NHEADS * TOK * TOK) return;
    int h  = p / (TOK * TOK);
    int mn = p % (TOK * TOK);
    out[p] = table[rel[mn] * NHEADS + h];
}

// ---------------- kernel 1: LN1 + window attention + proj + residual ----------------
// one block per window; 4 waves; wave w owns output rows [w*16, w*16+16)
__global__ void __launch_bounds__(256, 2) attn_kernel(
    const float* __restrict__ x,
    const float* __restrict__ g1, const float* __restrict__ b1,
    const bf16_t* __restrict__ qkv_p, const bf16_t* __restrict__ proj_p,
    const float* __restrict__ proj_b, const float* __restrict__ bias6,
    float* __restrict__ out) {

    __shared__ bf16_t s_xln[64 * XLD];        // 25600 B
    __shared__ bf16_t s_q[64 * QLD];          //  5120 B
    __shared__ bf16_t s_k[64 * QLD];          //  5120 B
    __shared__ bf16_t s_vT[32 * VLD];         //  4608 B
    __shared__ bf16_t s_p[4][16 * PLD];       //  5120 B   (per-wave)

    const int t    = threadIdx.x;
    const int w    = t >> 6;
    const int lane = t & 63;
    const int l15  = lane & 15;
    const int quad = lane >> 4;
    const int widx = blockIdx.x;
    const float scale = 0.17677669529663687f; // 32^-0.5

    const float* xw = x + (size_t)widx * (TOK * WDIM);

    // ---- LN1: 4 threads per row; rows 49..63 zero-filled ----
    {
        int r = t >> 2, l4 = t & 3;
        if (r < TOK) {
            const float* row = xw + r * WDIM + l4 * 48;
            float s = 0.f, sq = 0.f;
            #pragma unroll
            for (int i = 0; i < 12; i++) {
                float4 f = ((const float4*)row)[i];
                s  += f.x + f.y + f.z + f.w;
                sq += f.x*f.x + f.y*f.y + f.z*f.z + f.w*f.w;
            }
            s  += __shfl_xor(s, 1);  s  += __shfl_xor(s, 2);
            sq += __shfl_xor(sq, 1); sq += __shfl_xor(sq, 2);
            float mean = s * (1.f / WDIM);
            float rstd = rsqrtf(sq * (1.f / WDIM) - mean * mean + 1e-5f);
            #pragma unroll
            for (int i = 0; i < 12; i++) {
                float4 f = ((const float4*)row)[i];
                int c = l4 * 48 + i * 4;
                s_xln[r * XLD + c + 0] = (bf16_t)((f.x - mean) * rstd * g1[c+0] + b1[c+0]);
                s_xln[r * XLD + c + 1] = (bf16_t)((f.y - mean) * rstd * g1[c+1] + b1[c+1]);
                s_xln[r * XLD + c + 2] = (bf16_t)((f.z - mean) * rstd * g1[c+2] + b1[c+2]);
                s_xln[r * XLD + c + 3] = (bf16_t)((f.w - mean) * rstd * g1[c+3] + b1[c+3]);
            }
        } else {
            #pragma unroll
            for (int i = 0; i < 48; i++)
                s_xln[r * XLD + l4 * 48 + i] = (bf16_t)0.f;
        }
    }
    __syncthreads();

    const f32x4 z = {0.f, 0.f, 0.f, 0.f};
    f32x4 pacc[12];
    #pragma unroll
    for (int i = 0; i < 12; i++) pacc[i] = z;

    for (int h = 0; h < NHEADS; h++) {
        // ---- qkv GEMM: own 16 rows x 96 head-cols (Q|K|V each 32) ----
        f32x4 qa[6];
        #pragma unroll
        for (int i = 0; i < 6; i++) qa[i] = z;
        #pragma unroll
        for (int kb = 0; kb < 6; kb++) {
            bf16x8 a = *(const bf16x8*)&s_xln[(w * 16 + l15) * XLD + kb * 32 + quad * 8];
            #pragma unroll
            for (int gidx = 0; gidx < 3; gidx++) {
                int ntg = gidx * 12 + h * 2;
                #pragma unroll
                for (int i = 0; i < 2; i++) {
                    bf16x8 b = *(const bf16x8*)&qkv_p[(size_t)(((ntg + i) * 6 + kb) * 64 + lane) * 8];
                    qa[gidx * 2 + i] = mfma16(a, b, qa[gidx * 2 + i]);
                }
            }
        }
        // stage q, k, vT to LDS
        #pragma unroll
        for (int i = 0; i < 2; i++) {
            #pragma unroll
            for (int reg = 0; reg < 4; reg++) {
                int row = w * 16 + quad * 4 + reg;
                int d   = i * 16 + l15;
                s_q[row * QLD + d]  = (bf16_t)qa[0 + i][reg];
                s_k[row * QLD + d]  = (bf16_t)qa[2 + i][reg];
                s_vT[d * VLD + row] = (bf16_t)qa[4 + i][reg];
            }
        }
        __syncthreads();

        // ---- S = q k^T (own 16 rows x all 64 cols) ----
        f32x4 sa[4];
        {
            bf16x8 aq = *(const bf16x8*)&s_q[(w * 16 + l15) * QLD + quad * 8];
            #pragma unroll
            for (int nt = 0; nt < 4; nt++) {
                bf16x8 bk = *(const bf16x8*)&s_k[(nt * 16 + l15) * QLD + quad * 8];
                sa[nt] = mfma16(aq, bk, z);
            }
        }
        // ---- bias + masked softmax ----
        float p[4][4];
        const float* b6 = bias6 + h * (TOK * TOK);
        #pragma unroll
        for (int nt = 0; nt < 4; nt++) {
            int n  = nt * 16 + l15;
            int nc = (n < TOK) ? n : 0;
            #pragma unroll
            for (int reg = 0; reg < 4; reg++) {
                int mm = w * 16 + quad * 4 + reg;
                int mc = (mm < TOK) ? mm : 0;
                float bias = b6[mc * TOK + nc];
                p[nt][reg] = (n < TOK) ? (sa[nt][reg] * scale + bias) : -INFINITY;
            }
        }
        #pragma unroll
        for (int reg = 0; reg < 4; reg++) {
            float mx = fmaxf(fmaxf(p[0][reg], p[1][reg]), fmaxf(p[2][reg], p[3][reg]));
            mx = fmaxf(mx, __shfl_xor(mx, 1));
            mx = fmaxf(mx, __shfl_xor(mx, 2));
            mx = fmaxf(mx, __shfl_xor(mx, 4));
            mx = fmaxf(mx, __shfl_xor(mx, 8));
            float sum = 0.f;
            #pragma unroll
            for (int nt = 0; nt < 4; nt++) {
                float e = __expf(p[nt][reg] - mx);
                p[nt][reg] = e;
                sum += e;
            }
            sum += __shfl_xor(sum, 1);
            sum += __shfl_xor(sum, 2);
            sum += __shfl_xor(sum, 4);
            sum += __shfl_xor(sum, 8);
            float rinv = 1.f / sum;
            #pragma unroll
            for (int nt = 0; nt < 4; nt++) p[nt][reg] *= rinv;
        }
        // ---- PV via per-wave P round-trip (C-layout -> A-layout), n-chunked by 32 ----
        bf16_t* pw = s_p[w];
        f32x4 oa[2] = {z, z};
        #pragma unroll
        for (int half = 0; half < 2; half++) {
            #pragma unroll
            for (int i = 0; i < 2; i++) {
                int nt = half * 2 + i;
                #pragma unroll
                for (int reg = 0; reg < 4; reg++)
                    pw[(quad * 4 + reg) * PLD + i * 16 + l15] = (bf16_t)p[nt][reg];
            }
            bf16x8 ap = *(const bf16x8*)&pw[l15 * PLD + quad * 8];
            #pragma unroll
            for (int dt = 0; dt < 2; dt++) {
                bf16x8 bv = *(const bf16x8*)&s_vT[(dt * 16 + l15) * VLD + half * 32 + quad * 8];
                oa[dt] = mfma16(ap, bv, oa[dt]);
            }
        }
        // ---- attn-out round-trip, then proj partial: pacc += attn_h @ proj_w[h*32:,:] ----
        #pragma unroll
        for (int dt = 0; dt < 2; dt++)
            #pragma unroll
            for (int reg = 0; reg < 4; reg++)
                pw[(quad * 4 + reg) * PLD + dt * 16 + l15] = (bf16_t)oa[dt][reg];
        bf16x8 aat = *(const bf16x8*)&pw[l15 * PLD + quad * 8];
        #pragma unroll
        for (int nt = 0; nt < 12; nt++) {
            bf16x8 bp = *(const bf16x8*)&proj_p[(size_t)((nt * 6 + h) * 64 + lane) * 8];
            pacc[nt] = mfma16(aat, bp, pacc[nt]);
        }
        __syncthreads();   // protect s_q/s_k/s_vT before next head overwrites
    }

    // ---- epilogue: out = proj + proj_b + x ----
    float* ow = out + (size_t)widx * (TOK * WDIM);
    #pragma unroll
    for (int nt = 0; nt < 12; nt++) {
        int col = nt * 16 + l15;
        #pragma unroll
        for (int reg = 0; reg < 4; reg++) {
            int mm = w * 16 + quad * 4 + reg;
            if (mm < TOK)
                ow[mm * WDIM + col] = pacc[nt][reg] + proj_b[col] + xw[mm * WDIM + col];
        }
    }
}

// ---------------- kernel 2: LN2 + fc1 + gelu + fc2 + residual (in-place on d_out) ---
// one block per 64 rows (200704/64 = 3136); barrier-free (wave owns its 16 rows)
__global__ void __launch_bounds__(256, 2) mlp_kernel(
    float* __restrict__ xio,
    const float* __restrict__ g2, const float* __restrict__ b2,
    const bf16_t* __restrict__ fc1_p, const float* __restrict__ fc1_b,
    const bf16_t* __restrict__ fc2_p, const float* __restrict__ fc2_b) {

    __shared__ bf16_t s_x[64 * XLD];          // 25600 B
    __shared__ bf16_t s_h[4][16 * HLD];       // 33792 B (per-wave)

    const int t    = threadIdx.x;
    const int w    = t >> 6;
    const int lane = t & 63;
    const int l15  = lane & 15;
    const int quad = lane >> 4;
    float* xw = xio + (size_t)blockIdx.x * 64 * WDIM;

    // ---- LN2 ----
    {
        int r = t >> 2, l4 = t & 3;
        const float* row = xw + r * WDIM + l4 * 48;
        float s = 0.f, sq = 0.f;
        #pragma unroll
        for (int i = 0; i < 12; i++) {
            float4 f = ((const float4*)row)[i];
            s  += f.x + f.y + f.z + f.w;
            sq += f.x*f.x + f.y*f.y + f.z*f.z + f.w*f.w;
        }
        s  += __shfl_xor(s, 1);  s  += __shfl_xor(s, 2);
        sq += __shfl_xor(sq, 1); sq += __shfl_xor(sq, 2);
        float mean = s * (1.f / WDIM);
        float rstd = rsqrtf(sq * (1.f / WDIM) - mean * mean + 1e-5f);
        #pragma unroll
        for (int i = 0; i < 12; i++) {
            float4 f = ((const float4*)row)[i];
            int c = l4 * 48 + i * 4;
            s_x[r * XLD + c + 0] = (bf16_t)((f.x - mean) * rstd * g2[c+0] + b2[c+0]);
            s_x[r * XLD + c + 1] = (bf16_t)((f.y - mean) * rstd * g2[c+1] + b2[c+1]);
            s_x[r * XLD + c + 2] = (bf16_t)((f.z - mean) * rstd * g2[c+2] + b2[c+2]);
            s_x[r * XLD + c + 3] = (bf16_t)((f.w - mean) * rstd * g2[c+3] + b2[c+3]);
        }
    }
    // no barrier: wave w wrote exactly the rows it reads below

    const f32x4 z = {0.f, 0.f, 0.f, 0.f};
    f32x4 fa[12];
    #pragma unroll
    for (int i = 0; i < 12; i++) fa[i] = z;

    for (int ch = 0; ch < 3; ch++) {          // 768 = 3 chunks of 256 cols
        f32x4 ha[16];
        #pragma unroll
        for (int i = 0; i < 16; i++) ha[i] = z;
        #pragma unroll
        for (int kb = 0; kb < 6; kb++) {
            bf16x8 a = *(const bf16x8*)&s_x[(w * 16 + l15) * XLD + kb * 32 + quad * 8];
            #pragma unroll
            for (int i = 0; i < 16; i++) {
                int nt = ch * 16 + i;
                bf16x8 b = *(const bf16x8*)&fc1_p[(size_t)((nt * 6 + kb) * 64 + lane) * 8];
                ha[i] = mfma16(a, b, ha[i]);
            }
        }
        // gelu(exact) -> per-wave hbuf
        bf16_t* hw = s_h[w];
        #pragma unroll
        for (int i = 0; i < 16; i++) {
            int col = ch * 256 + i * 16 + l15;
            float fb = fc1_b[col];
            #pragma unroll
            for (int reg = 0; reg < 4; reg++) {
                float v = ha[i][reg] + fb;
                float gl = 0.5f * v * (1.f + erff(v * 0.70710678118654752f));
                hw[(quad * 4 + reg) * HLD + i * 16 + l15] = (bf16_t)gl;
            }
        }
        // fc2 partial over this chunk's 256 k values
        #pragma unroll
        for (int kc = 0; kc < 8; kc++) {
            bf16x8 a = *(const bf16x8*)&hw[l15 * HLD + kc * 32 + quad * 8];
            int kb = ch * 8 + kc;
            #pragma unroll
            for (int nt = 0; nt < 12; nt++) {
                bf16x8 b = *(const bf16x8*)&fc2_p[(size_t)((nt * 24 + kb) * 64 + lane) * 8];
                fa[nt] = mfma16(a, b, fa[nt]);
            }
        }
    }
    // ---- epilogue: out = fc2 + fc2_b + x' (in place) ----
    #pragma unroll
    for (int nt = 0; nt < 12; nt++) {
        int col = nt * 16 + l15;
        #pragma unroll
        for (int reg = 0; reg < 4; reg++) {
            int r = w * 16 + quad * 4 + reg;
            float* ptr = xw + r * WDIM + col;
            *ptr = fa[nt][reg] + fc2_b[col] + *ptr;
        }
    }
}

// ---------------- launch ------------------------------------------------------------
extern "C" void kernel_launch(void* const* d_in, const int* in_sizes, int n_in,
                              void* d_out, int out_size, void* d_ws, size_t ws_size,
                              hipStream_t stream) {
    const float* x      = (const float*)d_in[0];
    const float* ln1_g  = (const float*)d_in[1];
    const float* ln1_b  = (const float*)d_in[2];
    const float* qkv_w  = (const float*)d_in[3];
    const float* proj_w = (const float*)d_in[4];
    const float* proj_b = (const float*)d_in[5];
    const float* bias_t = (const float*)d_in[6];
    const float* ln2_g  = (const float*)d_in[7];
    const float* ln2_b  = (const float*)d_in[8];
    const float* fc1_w  = (const float*)d_in[9];
    const float* fc1_b  = (const float*)d_in[10];
    const float* fc2_w  = (const float*)d_in[11];
    const float* fc2_b  = (const float*)d_in[12];
    const int*   rel    = (const int*)d_in[13];
    float* out = (float*)d_out;

    char* ws = (char*)d_ws;
    bf16_t* qkv_p  = (bf16_t*)(ws);               // 110592 bf16 = 221184 B
    bf16_t* proj_p = (bf16_t*)(ws + 221184);      //  36864 bf16 =  73728 B
    bf16_t* fc1_p  = (bf16_t*)(ws + 294912);      // 147456 bf16 = 294912 B
    bf16_t* fc2_p  = (bf16_t*)(ws + 589824);      // 147456 bf16 = 294912 B
    float*  bias6  = (float*) (ws + 884736);      //  14406 f32  =  57624 B

    pack_w<<<432, 256, 0, stream>>>(qkv_w,  qkv_p,  192, 576, 110592);
    pack_w<<<144, 256, 0, stream>>>(proj_w, proj_p, 192, 192,  36864);
    pack_w<<<576, 256, 0, stream>>>(fc1_w,  fc1_p,  192, 768, 147456);
    pack_w<<<576, 256, 0, stream>>>(fc2_w,  fc2_p,  768, 192, 147456);
    make_bias6<<<57, 256, 0, stream>>>(bias_t, rel, bias6);

    attn_kernel<<<4096, 256, 0, stream>>>(x, ln1_g, ln1_b, qkv_p, proj_p, proj_b, bias6, out);
    mlp_kernel<<<3136, 256, 0, stream>>>(out, ln2_g, ln2_b, fc1_p, fc1_b, fc2_p, fc2_b);
}

// Round 2
// 852.889 us; speedup vs baseline: 1.6071x; 1.6071x over previous
//
#include <hip/hip_runtime.h>
#include <cmath>

#define TOK   49
#define WDIM  192
#define NHEADS 6
#define HID   768

typedef __bf16 bf16_t;
typedef bf16_t bf16x8 __attribute__((ext_vector_type(8)));
typedef float  f32x4  __attribute__((ext_vector_type(4)));

#define XLD  200  // 192 + 8 pad (row stride 400B = 4-bank offset per row)
#define QKLD 72   // 64 + 8 pad
#define VTLD 72
#define AOLD 72
#define PLD  40   // 32 + 8 pad
#define HLD2 200  // mlp hidden chunk 192 + 8 pad

__device__ __forceinline__ f32x4 mfma16(bf16x8 a, bf16x8 b, f32x4 c) {
    return __builtin_amdgcn_mfma_f32_16x16x32_bf16(a, b, c, 0, 0, 0);
}

__device__ __forceinline__ float gelu_f(float v) {
    // tanh-form gelu; max abs err vs erf-form ~3e-4 (threshold is 0.112)
    float u = 0.7978845608028654f * (v + 0.044715f * v * v * v);
    float e = __expf(2.f * u);
    float t = 1.f - 2.f / (e + 1.f);
    return 0.5f * v * (1.f + t);
}

// ---------------- prep: pack fp32 weight W[K][N] into bf16 MFMA-B fragment order ----
// p = ((nt*KB + kb)*64 + lane)*8 + j  <->  W[k = kb*32 + (lane>>4)*8 + j][n = nt*16 + (lane&15)]
__global__ void pack_w(const float* __restrict__ W, bf16_t* __restrict__ out,
                       int K, int N, int total) {
    int p = blockIdx.x * 256 + threadIdx.x;
    if (p >= total) return;
    int j    = p & 7;
    int lane = (p >> 3) & 63;
    int kbnt = p >> 9;
    int KB   = K >> 5;
    int kb   = kbnt % KB;
    int nt   = kbnt / KB;
    int n = nt * 16 + (lane & 15);
    int k = kb * 32 + (lane >> 4) * 8 + j;
    out[p] = (bf16_t)W[k * N + n];
}

__global__ void make_bias6(const float* __restrict__ table, const int* __restrict__ rel,
                           float* __restrict__ out) {
    int p = blockIdx.x * 256 + threadIdx.x;
    if (p >= NHEADS * TOK * TOK) return;
    int h  = p / (TOK * TOK);
    int mn = p % (TOK * TOK);
    out[p] = table[rel[mn] * NHEADS + h];
}

// ---------------- kernel 1: LN1 + window attention + proj + residual ----------------
// one block per window; 4 waves; head-PAIR loop; each wave computes ALL 64 rows
// for 3 of the pair's 12 qkv col-tiles (B fragments loaded once per block).
__global__ void __launch_bounds__(256, 2) attn_kernel(
    const float* __restrict__ x,
    const float* __restrict__ g1, const float* __restrict__ b1,
    const bf16_t* __restrict__ qkv_p, const bf16_t* __restrict__ proj_p,
    const float* __restrict__ proj_b, const float* __restrict__ bias6,
    float* __restrict__ out) {

    __shared__ bf16_t s_xln[64 * XLD];     // 25600 B
    __shared__ bf16_t s_q[64 * QKLD];      //  9216 B (pair: 64 cols)
    __shared__ bf16_t s_k[64 * QKLD];      //  9216 B
    __shared__ bf16_t s_vT[64 * VTLD];     //  9216 B  (vT[d][row])
    __shared__ bf16_t s_ao[64 * AOLD];     //  9216 B  (attn-out, pair cols)
    __shared__ bf16_t s_p[4][16 * PLD];    //  5120 B  (per-wave P buffer)

    const int t    = threadIdx.x;
    const int w    = t >> 6;
    const int lane = t & 63;
    const int l15  = lane & 15;
    const int quad = lane >> 4;
    const int widx = blockIdx.x;
    const float scale = 0.17677669529663687f; // 32^-0.5
    const f32x4 z = {0.f, 0.f, 0.f, 0.f};

    const float* xw = x + (size_t)widx * (TOK * WDIM);

    // ---- LN1: 4 threads per row; rows 49..63 zero-filled ----
    {
        int r = t >> 2, l4 = t & 3;
        if (r < TOK) {
            const float* row = xw + r * WDIM + l4 * 48;
            float s = 0.f, sq = 0.f;
            #pragma unroll
            for (int i = 0; i < 12; i++) {
                float4 f = ((const float4*)row)[i];
                s  += f.x + f.y + f.z + f.w;
                sq += f.x*f.x + f.y*f.y + f.z*f.z + f.w*f.w;
            }
            s  += __shfl_xor(s, 1);  s  += __shfl_xor(s, 2);
            sq += __shfl_xor(sq, 1); sq += __shfl_xor(sq, 2);
            float mean = s * (1.f / WDIM);
            float rstd = rsqrtf(sq * (1.f / WDIM) - mean * mean + 1e-5f);
            #pragma unroll
            for (int i = 0; i < 12; i++) {
                float4 f = ((const float4*)row)[i];
                int c = l4 * 48 + i * 4;
                s_xln[r * XLD + c + 0] = (bf16_t)((f.x - mean) * rstd * g1[c+0] + b1[c+0]);
                s_xln[r * XLD + c + 1] = (bf16_t)((f.y - mean) * rstd * g1[c+1] + b1[c+1]);
                s_xln[r * XLD + c + 2] = (bf16_t)((f.z - mean) * rstd * g1[c+2] + b1[c+2]);
                s_xln[r * XLD + c + 3] = (bf16_t)((f.w - mean) * rstd * g1[c+3] + b1[c+3]);
            }
        } else {
            #pragma unroll
            for (int i = 0; i < 48; i++)
                s_xln[r * XLD + l4 * 48 + i] = (bf16_t)0.f;
        }
    }
    __syncthreads();

    f32x4 pacc[4][3];
    #pragma unroll
    for (int rt = 0; rt < 4; rt++)
        #pragma unroll
        for (int j = 0; j < 3; j++) pacc[rt][j] = z;

    for (int pr = 0; pr < 3; pr++) {
        // ---- phase 1: qkv GEMM for head pair (2pr, 2pr+1) ----
        // pair col-tile np = g*4 + hh*2 + d16 (g: 0=q,1=k,2=v); wave owns np = w*3+j
        f32x4 qa[4][3];
        #pragma unroll
        for (int rt = 0; rt < 4; rt++)
            #pragma unroll
            for (int j = 0; j < 3; j++) qa[rt][j] = z;

        int ntg[3];
        #pragma unroll
        for (int j = 0; j < 3; j++) {
            int np = w * 3 + j;
            int g = np >> 2, hh = (np >> 1) & 1, d16 = np & 1;
            ntg[j] = g * 12 + (2 * pr + hh) * 2 + d16;
        }
        #pragma unroll
        for (int kb = 0; kb < 6; kb++) {
            bf16x8 a[4];
            #pragma unroll
            for (int rt = 0; rt < 4; rt++)
                a[rt] = *(const bf16x8*)&s_xln[(rt * 16 + l15) * XLD + kb * 32 + quad * 8];
            #pragma unroll
            for (int j = 0; j < 3; j++) {
                bf16x8 b = *(const bf16x8*)&qkv_p[(size_t)((ntg[j] * 6 + kb) * 64 + lane) * 8];
                #pragma unroll
                for (int rt = 0; rt < 4; rt++)
                    qa[rt][j] = mfma16(a[rt], b, qa[rt][j]);
            }
        }
        // stage q / k / vT (wave-uniform g per j -> no divergence)
        #pragma unroll
        for (int j = 0; j < 3; j++) {
            int np = w * 3 + j;
            int g = np >> 2;
            int pcol = ((np >> 1) & 1) * 32 + (np & 1) * 16 + l15;
            #pragma unroll
            for (int rt = 0; rt < 4; rt++)
                #pragma unroll
                for (int reg = 0; reg < 4; reg++) {
                    int row = rt * 16 + quad * 4 + reg;
                    bf16_t val = (bf16_t)qa[rt][j][reg];
                    if (g == 0)      s_q[row * QKLD + pcol] = val;
                    else if (g == 1) s_k[row * QKLD + pcol] = val;
                    else             s_vT[pcol * VTLD + row] = val;
                }
        }
        __syncthreads();

        // ---- phase 2: S, softmax, PV per head; wave owns rows w*16..+16 ----
        #pragma unroll
        for (int hh = 0; hh < 2; hh++) {
            int h = 2 * pr + hh;
            bf16x8 aq = *(const bf16x8*)&s_q[(w * 16 + l15) * QKLD + hh * 32 + quad * 8];
            f32x4 sa[4];
            #pragma unroll
            for (int nt = 0; nt < 4; nt++) {
                bf16x8 bk = *(const bf16x8*)&s_k[(nt * 16 + l15) * QKLD + hh * 32 + quad * 8];
                sa[nt] = mfma16(aq, bk, z);
            }
            float p[4][4];
            const float* b6 = bias6 + h * (TOK * TOK);
            #pragma unroll
            for (int nt = 0; nt < 4; nt++) {
                int n  = nt * 16 + l15;
                int nc = (n < TOK) ? n : 0;
                #pragma unroll
                for (int reg = 0; reg < 4; reg++) {
                    int mm = w * 16 + quad * 4 + reg;
                    int mc = (mm < TOK) ? mm : 0;
                    float bias = b6[mc * TOK + nc];
                    p[nt][reg] = (n < TOK) ? (sa[nt][reg] * scale + bias) : -INFINITY;
                }
            }
            #pragma unroll
            for (int reg = 0; reg < 4; reg++) {
                float mx = fmaxf(fmaxf(p[0][reg], p[1][reg]), fmaxf(p[2][reg], p[3][reg]));
                mx = fmaxf(mx, __shfl_xor(mx, 1));
                mx = fmaxf(mx, __shfl_xor(mx, 2));
                mx = fmaxf(mx, __shfl_xor(mx, 4));
                mx = fmaxf(mx, __shfl_xor(mx, 8));
                float sum = 0.f;
                #pragma unroll
                for (int nt = 0; nt < 4; nt++) {
                    float e = __expf(p[nt][reg] - mx);
                    p[nt][reg] = e;
                    sum += e;
                }
                sum += __shfl_xor(sum, 1);
                sum += __shfl_xor(sum, 2);
                sum += __shfl_xor(sum, 4);
                sum += __shfl_xor(sum, 8);
                float rinv = 1.f / sum;
                #pragma unroll
                for (int nt = 0; nt < 4; nt++) p[nt][reg] *= rinv;
            }
            // PV: per-wave P round-trip, n-chunked by 32
            bf16_t* pw = s_p[w];
            f32x4 oa[2] = {z, z};
            #pragma unroll
            for (int hf = 0; hf < 2; hf++) {
                #pragma unroll
                for (int i = 0; i < 2; i++) {
                    int nt = hf * 2 + i;
                    #pragma unroll
                    for (int reg = 0; reg < 4; reg++)
                        pw[(quad * 4 + reg) * PLD + i * 16 + l15] = (bf16_t)p[nt][reg];
                }
                bf16x8 ap = *(const bf16x8*)&pw[l15 * PLD + quad * 8];
                #pragma unroll
                for (int dt = 0; dt < 2; dt++) {
                    bf16x8 bv = *(const bf16x8*)&s_vT[(hh * 32 + dt * 16 + l15) * VTLD + hf * 32 + quad * 8];
                    oa[dt] = mfma16(ap, bv, oa[dt]);
                }
            }
            #pragma unroll
            for (int dt = 0; dt < 2; dt++)
                #pragma unroll
                for (int reg = 0; reg < 4; reg++)
                    s_ao[(w * 16 + quad * 4 + reg) * AOLD + hh * 32 + dt * 16 + l15] = (bf16_t)oa[dt][reg];
        }
        __syncthreads();

        // ---- phase 3: proj partial over this pair's 64 attn-out cols ----
        #pragma unroll
        for (int kbp = 0; kbp < 2; kbp++) {
            bf16x8 a[4];
            #pragma unroll
            for (int rt = 0; rt < 4; rt++)
                a[rt] = *(const bf16x8*)&s_ao[(rt * 16 + l15) * AOLD + kbp * 32 + quad * 8];
            #pragma unroll
            for (int j = 0; j < 3; j++) {
                int nt = w * 3 + j;
                bf16x8 b = *(const bf16x8*)&proj_p[(size_t)((nt * 6 + pr * 2 + kbp) * 64 + lane) * 8];
                #pragma unroll
                for (int rt = 0; rt < 4; rt++)
                    pacc[rt][j] = mfma16(a[rt], b, pacc[rt][j]);
            }
        }
        // no barrier needed here: next pair's phase-1 only touches s_xln/s_q/s_k/s_vT,
        // and its post-staging barrier orders everything before s_ao is rewritten.
    }

    // ---- epilogue: out = proj + proj_b + x  (wave writes all 64 rows x its 48 cols)
    float* ow = out + (size_t)widx * (TOK * WDIM);
    #pragma unroll
    for (int rt = 0; rt < 4; rt++)
        #pragma unroll
        for (int j = 0; j < 3; j++) {
            int col = (w * 3 + j) * 16 + l15;
            #pragma unroll
            for (int reg = 0; reg < 4; reg++) {
                int mm = rt * 16 + quad * 4 + reg;
                if (mm < TOK)
                    ow[mm * WDIM + col] = pacc[rt][j][reg] + proj_b[col] + xw[mm * WDIM + col];
            }
        }
}

// ---------------- kernel 2: LN2 + fc1 + gelu + fc2 + residual (in-place on d_out) ---
// 64 rows/block; hidden dim chunked by 192; 4x3 register blocking over all 64 rows.
__global__ void __launch_bounds__(256, 2) mlp_kernel(
    float* __restrict__ xio,
    const float* __restrict__ g2, const float* __restrict__ b2,
    const bf16_t* __restrict__ fc1_p, const float* __restrict__ fc1_b,
    const bf16_t* __restrict__ fc2_p, const float* __restrict__ fc2_b) {

    __shared__ bf16_t s_x[64 * XLD];       // 25600 B
    __shared__ bf16_t s_h[64 * HLD2];      // 25600 B -> 51.2 KB total (3 blocks/CU possible)

    const int t    = threadIdx.x;
    const int w    = t >> 6;
    const int lane = t & 63;
    const int l15  = lane & 15;
    const int quad = lane >> 4;
    const f32x4 z = {0.f, 0.f, 0.f, 0.f};
    float* xw = xio + (size_t)blockIdx.x * 64 * WDIM;

    // ---- LN2 ----
    {
        int r = t >> 2, l4 = t & 3;
        const float* row = xw + r * WDIM + l4 * 48;
        float s = 0.f, sq = 0.f;
        #pragma unroll
        for (int i = 0; i < 12; i++) {
            float4 f = ((const float4*)row)[i];
            s  += f.x + f.y + f.z + f.w;
            sq += f.x*f.x + f.y*f.y + f.z*f.z + f.w*f.w;
        }
        s  += __shfl_xor(s, 1);  s  += __shfl_xor(s, 2);
        sq += __shfl_xor(sq, 1); sq += __shfl_xor(sq, 2);
        float mean = s * (1.f / WDIM);
        float rstd = rsqrtf(sq * (1.f / WDIM) - mean * mean + 1e-5f);
        #pragma unroll
        for (int i = 0; i < 12; i++) {
            float4 f = ((const float4*)row)[i];
            int c = l4 * 48 + i * 4;
            s_x[r * XLD + c + 0] = (bf16_t)((f.x - mean) * rstd * g2[c+0] + b2[c+0]);
            s_x[r * XLD + c + 1] = (bf16_t)((f.y - mean) * rstd * g2[c+1] + b2[c+1]);
            s_x[r * XLD + c + 2] = (bf16_t)((f.z - mean) * rstd * g2[c+2] + b2[c+2]);
            s_x[r * XLD + c + 3] = (bf16_t)((f.w - mean) * rstd * g2[c+3] + b2[c+3]);
        }
    }
    __syncthreads();   // waves now read all 64 rows

    f32x4 fa[4][3];
    #pragma unroll
    for (int rt = 0; rt < 4; rt++)
        #pragma unroll
        for (int j = 0; j < 3; j++) fa[rt][j] = z;

    for (int ch = 0; ch < 4; ch++) {       // 768 = 4 chunks of 192 hidden cols
        // ---- fc1 chunk: wave owns 3 of 12 col-tiles, all 64 rows ----
        f32x4 ha[4][3];
        #pragma unroll
        for (int rt = 0; rt < 4; rt++)
            #pragma unroll
            for (int j = 0; j < 3; j++) ha[rt][j] = z;
        #pragma unroll
        for (int kb = 0; kb < 6; kb++) {
            bf16x8 a[4];
            #pragma unroll
            for (int rt = 0; rt < 4; rt++)
                a[rt] = *(const bf16x8*)&s_x[(rt * 16 + l15) * XLD + kb * 32 + quad * 8];
            #pragma unroll
            for (int j = 0; j < 3; j++) {
                int ntg = ch * 12 + w * 3 + j;
                bf16x8 b = *(const bf16x8*)&fc1_p[(size_t)((ntg * 6 + kb) * 64 + lane) * 8];
                #pragma unroll
                for (int rt = 0; rt < 4; rt++)
                    ha[rt][j] = mfma16(a[rt], b, ha[rt][j]);
            }
        }
        // gelu -> s_h
        #pragma unroll
        for (int j = 0; j < 3; j++) {
            int colg = (ch * 12 + w * 3 + j) * 16 + l15;
            float fb = fc1_b[colg];
            int colc = (w * 3 + j) * 16 + l15;
            #pragma unroll
            for (int rt = 0; rt < 4; rt++)
                #pragma unroll
                for (int reg = 0; reg < 4; reg++) {
                    float v = ha[rt][j][reg] + fb;
                    s_h[(rt * 16 + quad * 4 + reg) * HLD2 + colc] = (bf16_t)gelu_f(v);
                }
        }
        __syncthreads();
        // ---- fc2 partial over this chunk's 192 k values ----
        #pragma unroll
        for (int kc = 0; kc < 6; kc++) {
            bf16x8 a[4];
            #pragma unroll
            for (int rt = 0; rt < 4; rt++)
                a[rt] = *(const bf16x8*)&s_h[(rt * 16 + l15) * HLD2 + kc * 32 + quad * 8];
            int kbg = ch * 6 + kc;
            #pragma unroll
            for (int j = 0; j < 3; j++) {
                int nt = w * 3 + j;
                bf16x8 b = *(const bf16x8*)&fc2_p[(size_t)((nt * 24 + kbg) * 64 + lane) * 8];
                #pragma unroll
                for (int rt = 0; rt < 4; rt++)
                    fa[rt][j] = mfma16(a[rt], b, fa[rt][j]);
            }
        }
        __syncthreads();   // before next chunk overwrites s_h
    }

    // ---- epilogue: out = fc2 + fc2_b + x' (in place) ----
    #pragma unroll
    for (int rt = 0; rt < 4; rt++)
        #pragma unroll
        for (int j = 0; j < 3; j++) {
            int col = (w * 3 + j) * 16 + l15;
            #pragma unroll
            for (int reg = 0; reg < 4; reg++) {
                int r = rt * 16 + quad * 4 + reg;
                float* ptr = xw + r * WDIM + col;
                *ptr = fa[rt][j][reg] + fc2_b[col] + *ptr;
            }
        }
}

// ---------------- launch ------------------------------------------------------------
extern "C" void kernel_launch(void* const* d_in, const int* in_sizes, int n_in,
                              void* d_out, int out_size, void* d_ws, size_t ws_size,
                              hipStream_t stream) {
    const float* x      = (const float*)d_in[0];
    const float* ln1_g  = (const float*)d_in[1];
    const float* ln1_b  = (const float*)d_in[2];
    const float* qkv_w  = (const float*)d_in[3];
    const float* proj_w = (const float*)d_in[4];
    const float* proj_b = (const float*)d_in[5];
    const float* bias_t = (const float*)d_in[6];
    const float* ln2_g  = (const float*)d_in[7];
    const float* ln2_b  = (const float*)d_in[8];
    const float* fc1_w  = (const float*)d_in[9];
    const float* fc1_b  = (const float*)d_in[10];
    const float* fc2_w  = (const float*)d_in[11];
    const float* fc2_b  = (const float*)d_in[12];
    const int*   rel    = (const int*)d_in[13];
    float* out = (float*)d_out;

    char* ws = (char*)d_ws;
    bf16_t* qkv_p  = (bf16_t*)(ws);               // 110592 bf16 = 221184 B
    bf16_t* proj_p = (bf16_t*)(ws + 221184);      //  36864 bf16 =  73728 B
    bf16_t* fc1_p  = (bf16_t*)(ws + 294912);      // 147456 bf16 = 294912 B
    bf16_t* fc2_p  = (bf16_t*)(ws + 589824);      // 147456 bf16 = 294912 B
    float*  bias6  = (float*) (ws + 884736);      //  14406 f32  =  57624 B

    pack_w<<<432, 256, 0, stream>>>(qkv_w,  qkv_p,  192, 576, 110592);
    pack_w<<<144, 256, 0, stream>>>(proj_w, proj_p, 192, 192,  36864);
    pack_w<<<576, 256, 0, stream>>>(fc1_w,  fc1_p,  192, 768, 147456);
    pack_w<<<576, 256, 0, stream>>>(fc2_w,  fc2_p,  768, 192, 147456);
    make_bias6<<<57, 256, 0, stream>>>(bias_t, rel, bias6);

    attn_kernel<<<4096, 256, 0, stream>>>(x, ln1_g, ln1_b, qkv_p, proj_p, proj_b, bias6, out);
    mlp_kernel<<<3136, 256, 0, stream>>>(out, ln2_g, ln2_b, fc1_p, fc1_b, fc2_p, fc2_b);
}